// Round 2
// 308.672 us; speedup vs baseline: 1.0801x; 1.0801x over previous
//
#include <hip/hip_runtime.h>
#include <math.h>

#define SEQ    2048
#define EMBED  1024
#define HEADS  16
#define HDIM   64
#define BATCH  4
#define ROWS   (BATCH * SEQ)    // 8192
#define BH     (BATCH * HEADS)  // 64

typedef _Float16 f16;
typedef __attribute__((ext_vector_type(8))) _Float16 f16x8;
typedef __attribute__((ext_vector_type(4))) _Float16 f16x4;
typedef __attribute__((ext_vector_type(4))) float    f32x4;

#define LOG2E_10 0.14426950408889634f   // log2(e)/10

// fast 2^x / log2(x) via the HW transcendental unit
__device__ __forceinline__ float fast_exp2(float x) { return __builtin_amdgcn_exp2f(x); }
__device__ __forceinline__ float fast_log2(float x) { return __builtin_amdgcn_logf(x); }

// async global->LDS copy, 16B per lane. LDS dest = uniform base + lane*16.
__device__ __forceinline__ void async16(void* l, const void* g) {
    __builtin_amdgcn_global_load_lds(
        (__attribute__((address_space(1))) void*)(uintptr_t)g,
        (__attribute__((address_space(3))) void*)(uint32_t)(uintptr_t)l,
        16, 0, 0);
}
// 4B per lane (for small fp32 vectors like lg tiles)
__device__ __forceinline__ void async4(void* l, const void* g) {
    __builtin_amdgcn_global_load_lds(
        (__attribute__((address_space(1))) void*)(uintptr_t)g,
        (__attribute__((address_space(3))) void*)(uint32_t)(uintptr_t)l,
        4, 0, 0);
}

__device__ __forceinline__ f32x4 mfma16(f16x8 a, f16x8 b, f32x4 c) {
    return __builtin_amdgcn_mfma_f32_16x16x32_f16(a, b, c, 0, 0, 0);
}

// ---------------------------------------------------------------------------
// Kernel 0: fp32 -> fp16 convert. x -> xh [8192][1024]; Wq/Wk/Wv -> Wh
// concatenated [3072][1024]. Memory-bound, ~15us.
// ---------------------------------------------------------------------------
#define NX4 (ROWS * EMBED / 4)          // 2097152
#define NW4 (EMBED * EMBED / 4)         // 262144
__global__ __launch_bounds__(256) void cvt_kernel(
    const float* __restrict__ x,
    const float* __restrict__ Wq, const float* __restrict__ Wk,
    const float* __restrict__ Wv,
    f16* __restrict__ xh, f16* __restrict__ Wh)
{
    int i = blockIdx.x * 256 + threadIdx.x;
    const float4* src; f16* dst; int j;
    if (i < NX4)              { src = (const float4*)x;  dst = xh;                j = i; }
    else if (i < NX4 + NW4)   { src = (const float4*)Wq; dst = Wh;                j = i - NX4; }
    else if (i < NX4 + 2*NW4) { src = (const float4*)Wk; dst = Wh + EMBED*EMBED;  j = i - NX4 - NW4; }
    else                      { src = (const float4*)Wv; dst = Wh + 2*EMBED*EMBED;j = i - NX4 - 2*NW4; }
    float4 v = src[j];
    f16x4 h;
    h[0] = (f16)v.x; h[1] = (f16)v.y; h[2] = (f16)v.z; h[3] = (f16)v.w;
    *(f16x4*)(dst + (size_t)j * 4) = h;
}

// ---------------------------------------------------------------------------
// Kernel 1: fused QKV projection GEMM (f16 MFMA, m97 structure).
// C[8192][3072] = xh @ Wh^T + bias. 128x128 tile, BK=32, global_load_lds w=16.
// 64B LDS rows are already bank-conflict-free -- no swizzle needed here.
// Epilogue: Q,K -> [bh][s][d] fp16; V -> transposed Vt [bh][d][s] fp16.
// ---------------------------------------------------------------------------
__global__ __launch_bounds__(256) void proj_kernel(
    const f16* __restrict__ A,   // [8192][1024]
    const f16* __restrict__ W,   // [3072][1024]
    const float* __restrict__ bq, const float* __restrict__ bk,
    const float* __restrict__ bv,
    f16* __restrict__ Qh, f16* __restrict__ Kh, f16* __restrict__ Vt)
{
    __shared__ f16 As[128 * 32];   // [row][32k], rows 64B, unpadded (glds layout)
    __shared__ f16 Bs[128 * 32];

    const int t = threadIdx.x, wv = t >> 6, lane = t & 63;
    const int lm = lane & 15, quad = lane >> 4;
    const int r0 = blockIdx.x * 128, c0 = blockIdx.y * 128;
    const int wm = wv & 1, wn = wv >> 1;

    // staging: each wave stages 32 rows of A and B (2 x 16-row instructions)
    const int srow = wv * 32 + (lane >> 2);
    const int sch  = (lane & 3) * 8;     // f16 units (16B chunks)
    const f16* gA = A + (size_t)(r0 + srow) * EMBED + sch;
    const f16* gB = W + (size_t)(c0 + srow) * EMBED + sch;
    f16* lA = As + wv * 1024;
    f16* lB = Bs + wv * 1024;

    f32x4 acc[4][4];
#pragma unroll
    for (int i = 0; i < 4; ++i)
#pragma unroll
        for (int j = 0; j < 4; ++j) acc[i][j] = (f32x4){0.f, 0.f, 0.f, 0.f};

    for (int kk = 0; kk < EMBED; kk += 32) {
        __syncthreads();
        async16(lA,        gA + kk);
        async16(lA + 512,  gA + 16 * EMBED + kk);
        async16(lB,        gB + kk);
        async16(lB + 512,  gB + 16 * EMBED + kk);
        __syncthreads();

        f16x8 af[4], bf[4];
#pragma unroll
        for (int i = 0; i < 4; ++i)
            af[i] = *(const f16x8*)&As[(wm * 64 + i * 16 + lm) * 32 + quad * 8];
#pragma unroll
        for (int i = 0; i < 4; ++i)
            bf[i] = *(const f16x8*)&Bs[(wn * 64 + i * 16 + lm) * 32 + quad * 8];
#pragma unroll
        for (int mi = 0; mi < 4; ++mi)
#pragma unroll
            for (int ni = 0; ni < 4; ++ni)
                acc[mi][ni] = mfma16(af[mi], bf[ni], acc[mi][ni]);
    }

    // epilogue: bias + cvt + scatter into attention layouts
    const int z = c0 >> 10;              // 0=Q 1=K 2=V (128 | 1024 so no straddle)
    const float* bias = (z == 0) ? bq : (z == 1) ? bk : bv;
#pragma unroll
    for (int ni = 0; ni < 4; ++ni) {
        int col = c0 + wn * 64 + ni * 16 + lm;
        int cz  = col & 1023;
        float bb = bias[cz];
        int h = cz >> 6, d = cz & 63;
#pragma unroll
        for (int mi = 0; mi < 4; ++mi) {
            int rbase = r0 + wm * 64 + mi * 16 + quad * 4;
            int b = rbase >> 11, s = rbase & 2047;   // 4 rows stay in same b
            if (z < 2) {
                f16* O = (z == 0) ? Qh : Kh;
                size_t base = ((size_t)(b * HEADS + h) * SEQ + s) * HDIM + d;
#pragma unroll
                for (int r = 0; r < 4; ++r)
                    O[base + (size_t)r * HDIM] = (f16)(acc[mi][ni][r] + bb);
            } else {
                f16x4 pk;
#pragma unroll
                for (int r = 0; r < 4; ++r) pk[r] = (f16)(acc[mi][ni][r] + bb);
                *(f16x4*)&Vt[((size_t)(b * HEADS + h) * HDIM + d) * SEQ + s] = pk;
            }
        }
    }
}

// ---------------------------------------------------------------------------
// Kernel 2: column stats. lg[bh][k] = 10 - log2( sum_q exp(S[q,k]/10) ).
// (out_kernel consumes this as an exp2 bias: exp(S/10)*1024/colsum
//  == exp2(S*log2e/10 + lg).)
// grid (16, 64): block owns 128 k-cols; K-frags pinned in regs; q swept in
// 64-row LDS tiles. S via f16 MFMA (D[m=q][n=k]); colsum reduced over quads.
//
// LDS tiles have 128B rows -> XOR-swizzle (T2): global_load_lds writes
// linearly, so the swizzle is applied by permuting the per-lane GLOBAL source
// chunk (chunk c of row r holds global chunk c^(r&7)) and XOR-ing reads.
// ---------------------------------------------------------------------------
__global__ __launch_bounds__(256) void stats_kernel(
    const f16* __restrict__ Qh, const f16* __restrict__ Kh,
    float* __restrict__ lgv)
{
    __shared__ f16 Ks[128 * 64];   // [kcol][d] rows 128B, chunk-swizzled
    __shared__ f16 Qs[64 * 64];    // [q][d], chunk-swizzled

    const int t = threadIdx.x, wv = t >> 6, lane = t & 63;
    const int lm = lane & 15, quad = lane >> 4;
    const int bh = blockIdx.y, k0 = blockIdx.x * 128;
    const int grow = lane >> 3;                      // row within 8-row group
    const int gsw  = ((lane & 7) ^ grow) * 8;        // swizzled 16B source chunk
    const int rs   = lm & 7;                         // read-side row swizzle key
    const size_t base = (size_t)bh * SEQ * HDIM;

#pragma unroll
    for (int i = 0; i < 4; ++i) {
        int g = wv * 4 + i;
        async16(Ks + g * 512, Kh + base + (size_t)(k0 + g * 8 + grow) * HDIM + gsw);
    }
    __syncthreads();

    f16x8 kf[2][2];   // [coltile][dstep] -- stays in registers all sweep
#pragma unroll
    for (int ct = 0; ct < 2; ++ct)
#pragma unroll
        for (int ds = 0; ds < 2; ++ds)
            kf[ct][ds] = *(const f16x8*)&Ks[(wv * 32 + ct * 16 + lm) * 64
                                            + (((ds * 4 + quad) ^ rs) << 3)];

    float cs0 = 0.f, cs1 = 0.f;
    for (int q0 = 0; q0 < SEQ; q0 += 64) {
        __syncthreads();
#pragma unroll
        for (int i = 0; i < 2; ++i) {
            int g = wv * 2 + i;
            async16(Qs + g * 512, Qh + base + (size_t)(q0 + g * 8 + grow) * HDIM + gsw);
        }
        __syncthreads();
#pragma unroll
        for (int qt = 0; qt < 4; ++qt) {
            f16x8 a0 = *(const f16x8*)&Qs[(qt * 16 + lm) * 64 + ((quad ^ rs) << 3)];
            f16x8 a1 = *(const f16x8*)&Qs[(qt * 16 + lm) * 64 + (((4 + quad) ^ rs) << 3)];
            f32x4 c0v = (f32x4){0.f, 0.f, 0.f, 0.f};
            f32x4 c1v = (f32x4){0.f, 0.f, 0.f, 0.f};
            c0v = mfma16(a0, kf[0][0], c0v); c0v = mfma16(a1, kf[0][1], c0v);
            c1v = mfma16(a0, kf[1][0], c1v); c1v = mfma16(a1, kf[1][1], c1v);
#pragma unroll
            for (int r = 0; r < 4; ++r) {
                cs0 += fast_exp2(c0v[r] * LOG2E_10);
                cs1 += fast_exp2(c1v[r] * LOG2E_10);
            }
        }
    }
    // reduce the quad dimension (rows of the C tiles) across lanes
    cs0 += __shfl_xor(cs0, 16, 64); cs0 += __shfl_xor(cs0, 32, 64);
    cs1 += __shfl_xor(cs1, 16, 64); cs1 += __shfl_xor(cs1, 32, 64);
    if (quad == 0) {
        lgv[(size_t)bh * SEQ + k0 + wv * 32 + lm]      = 10.0f - fast_log2(cs0);
        lgv[(size_t)bh * SEQ + k0 + wv * 32 + 16 + lm] = 10.0f - fast_log2(cs1);
    }
}

// ---------------------------------------------------------------------------
// Kernel 3: out[q,d] = (1/1024) * sum_k P''[q,k] * V[k,d],
//           P'' = exp2(S*log2e/10 + lg[k])  (fp16, range [6e-3, 20]).
// grid (16, 64): block = 128 q rows (32/wave), sweep k in 64-tiles.
// Computes S^T = K.Q^T so C-layout rows = k -> pack 4 consecutive-k P vals
// into ds_write_b64 into padded (72 f16/row) per-wave P region; then P @ Vt.
// Ks/Vs/Q-staging tiles (128B rows) are chunk-XOR-swizzled like stats_kernel;
// the P region (144B rows) is naturally 2-way (free) and stays linear.
// ---------------------------------------------------------------------------
__global__ __launch_bounds__(256) void out_kernel(
    const f16* __restrict__ Qh, const f16* __restrict__ Kh,
    const f16* __restrict__ Vt, const float* __restrict__ lgv,
    float* __restrict__ out)
{
    __shared__ f16 Ps[4 * 32 * 72];   // Q staging (swizzled) then P (padded 72)
    __shared__ f16 Ks[64 * 64];       // [k][d], chunk-swizzled
    __shared__ f16 Vs[64 * 64];       // [d][s-chunk] (from Vt), chunk-swizzled
    __shared__ float Ls[64];

    const int t = threadIdx.x, wv = t >> 6, lane = t & 63;
    const int lm = lane & 15, quad = lane >> 4;
    const int bh = blockIdx.y, q0 = blockIdx.x * 128;
    const int b = bh >> 4, h = bh & 15;
    const int grow = lane >> 3;
    const int gsw  = ((lane & 7) ^ grow) * 8;        // swizzled 16B source chunk
    const int rs   = lm & 7;                         // read-side row swizzle key
    const size_t base = (size_t)bh * SEQ * HDIM;   // same stride for Qh/Kh/Vt

    // stage Q[128][64] (swizzled rows of 64); each wave stages its own 32 rows
#pragma unroll
    for (int i = 0; i < 4; ++i) {
        int g = wv * 4 + i;
        async16(Ps + g * 512, Qh + base + (size_t)(q0 + g * 8 + grow) * HDIM + gsw);
    }
    __syncthreads();
    f16x8 qa[2][2];   // Q fragments, pinned in regs (also reused as B-operand)
#pragma unroll
    for (int qs = 0; qs < 2; ++qs)
#pragma unroll
        for (int ds = 0; ds < 2; ++ds)
            qa[qs][ds] = *(const f16x8*)&Ps[(wv * 32 + qs * 16 + lm) * 64
                                            + (((ds * 4 + quad) ^ rs) << 3)];

    f32x4 oacc[2][4];
#pragma unroll
    for (int i = 0; i < 2; ++i)
#pragma unroll
        for (int j = 0; j < 4; ++j) oacc[i][j] = (f32x4){0.f, 0.f, 0.f, 0.f};

    f16* Pw = Ps + wv * (32 * 72);    // per-wave padded P region

    for (int k0 = 0; k0 < SEQ; k0 += 64) {
        __syncthreads();   // drains everyone's LDS reads (incl. iter-0 qa reads)
#pragma unroll
        for (int i = 0; i < 2; ++i) {
            int g = wv * 2 + i;
            async16(Ks + g * 512, Kh + base + (size_t)(k0 + g * 8 + grow) * HDIM + gsw);
            async16(Vs + g * 512, Vt + base + (size_t)(g * 8 + grow) * SEQ + k0 + gsw);
        }
        if (wv == 0) async4(Ls, lgv + (size_t)bh * SEQ + k0 + lane);
        __syncthreads();

        // S^T tiles: D[m=k][n=q] = K . Q^T; exp2(s*log2e/10 + lg) -> P[q][k]
#pragma unroll
        for (int ct = 0; ct < 4; ++ct) {
            int krow = ct * 16 + lm;
            f16x8 kf0 = *(const f16x8*)&Ks[krow * 64 + ((quad ^ rs) << 3)];
            f16x8 kf1 = *(const f16x8*)&Ks[krow * 64 + (((4 + quad) ^ rs) << 3)];
            float lg[4];
#pragma unroll
            for (int r = 0; r < 4; ++r) lg[r] = Ls[ct * 16 + quad * 4 + r];
#pragma unroll
            for (int qs = 0; qs < 2; ++qs) {
                f32x4 s4 = (f32x4){0.f, 0.f, 0.f, 0.f};
                s4 = mfma16(kf0, qa[qs][0], s4);
                s4 = mfma16(kf1, qa[qs][1], s4);
                f16x4 pk;
#pragma unroll
                for (int r = 0; r < 4; ++r)
                    pk[r] = (f16)fast_exp2(s4[r] * LOG2E_10 + lg[r]);
                // row q = qs*16+lm, cols k = ct*16+quad*4..+3 (contiguous, 8B store)
                *(f16x4*)&Pw[(qs * 16 + lm) * 72 + ct * 16 + quad * 4] = pk;
            }
        }
        // PV: D[m=q][n=d] = P @ Vt  (same-wave DS ordering makes P visible)
#pragma unroll
        for (int ks = 0; ks < 2; ++ks) {
            f16x8 pa0 = *(const f16x8*)&Pw[(lm) * 72 + ks * 32 + quad * 8];
            f16x8 pa1 = *(const f16x8*)&Pw[(16 + lm) * 72 + ks * 32 + quad * 8];
#pragma unroll
            for (int dt = 0; dt < 4; ++dt) {
                f16x8 vb = *(const f16x8*)&Vs[(dt * 16 + lm) * 64
                                              + (((ks * 4 + quad) ^ rs) << 3)];
                oacc[0][dt] = mfma16(pa0, vb, oacc[0][dt]);
                oacc[1][dt] = mfma16(pa1, vb, oacc[1][dt]);
            }
        }
    }

    const float inv1024 = 1.0f / 1024.0f;
#pragma unroll
    for (int qt = 0; qt < 2; ++qt)
#pragma unroll
        for (int dt = 0; dt < 4; ++dt) {
            int col = h * HDIM + dt * 16 + lm;
#pragma unroll
            for (int r = 0; r < 4; ++r) {
                int s = q0 + wv * 32 + qt * 16 + quad * 4 + r;
                out[((size_t)b * SEQ + s) * EMBED + col] = oacc[qt][dt][r] * inv1024;
            }
        }
}

extern "C" void kernel_launch(void* const* d_in, const int* in_sizes, int n_in,
                              void* d_out, int out_size, void* d_ws, size_t ws_size,
                              hipStream_t stream) {
    const float* x  = (const float*)d_in[0];
    const float* Wq = (const float*)d_in[1];
    const float* bq = (const float*)d_in[2];
    const float* Wk = (const float*)d_in[3];
    const float* bk = (const float*)d_in[4];
    const float* Wv = (const float*)d_in[5];
    const float* bv = (const float*)d_in[6];
    float* out = (float*)d_out;

    f16* xh = (f16*)d_ws;                          // 8388608
    f16* Wh = xh + (size_t)ROWS * EMBED;           // 3145728
    f16* Qh = Wh + (size_t)3 * EMBED * EMBED;      // 8388608
    f16* Kh = Qh + (size_t)BH * SEQ * HDIM;        // 8388608
    f16* Vt = Kh + (size_t)BH * SEQ * HDIM;        // 8388608
    float* lgv = (float*)(Vt + (size_t)BH * SEQ * HDIM);   // 131072 fp32
    // total ws use ~70.5 MB

    cvt_kernel<<<(NX4 + 3 * NW4) / 256, 256, 0, stream>>>(x, Wq, Wk, Wv, xh, Wh);
    proj_kernel<<<dim3(ROWS / 128, 3 * EMBED / 128), 256, 0, stream>>>(
        xh, Wh, bq, bk, bv, Qh, Kh, Vt);
    stats_kernel<<<dim3(SEQ / 128, BH), 256, 0, stream>>>(Qh, Kh, lgv);
    out_kernel<<<dim3(SEQ / 128, BH), 256, 0, stream>>>(Qh, Kh, Vt, lgv, out);
}